// Round 1
// baseline (1068.214 us; speedup 1.0000x reference)
//
#include <hip/hip_runtime.h>
#include <hip/hip_fp16.h>

// LSTM B=256,T=512,IN=64,H=128,L=2 + FC.
//  K0 cvt       : x, w_ih0, w_ih1 -> fp16 (ws)
//  KG (MFMA)    : xg0 = x16.Wih0^T + bias   [131072,512] fp16 (ws)
//  KR (L0)      : recurrent (MFMA broadcast-row engine), writes h0_all fp16
//  KG (MFMA)    : xg1 = h0_all.Wih1^T + bias (overwrites xg buffer)
//  KR (L1)      : recurrent + fused FC -> out
//
// KR v2 (this round): per step, gates[512] = h[128] @ Whh^T computed by
// mfma_f32_16x16x32_f16 with ALL 16 A-rows = h (quad-broadcast ds_read_b128,
// conflict-free). Wave w owns n-tiles {g*128 + w*16}, g=0..3, so lane c of
// wave w holds the complete (i,f,g,o) gate quad of unit w*16+c in
// acc[0..3][0] -- no gacts LDS round-trip, no shfl combine, ONE barrier per
// step (double-buffered hbuf). Whh lives in 64 VGPRs of B-frags. xg is
// prefetched 2 steps ahead. Replaces the 64x v_dot2 engine (~512 cyc/SIMD
// issue + 2 barriers + shfl) with 16 MFMA (~77 cyc, separate pipe).

#define TT 512
#define MM (256 * 512)   // 131072 rows for the batched GEMMs

typedef _Float16 f16x2 __attribute__((ext_vector_type(2)));
typedef _Float16 f16x8 __attribute__((ext_vector_type(8)));
typedef float f32x4 __attribute__((ext_vector_type(4)));

__device__ __forceinline__ float tanh_f(float x) {
    float e = __expf(2.0f * x);
    return 1.0f - 2.0f * __builtin_amdgcn_rcpf(e + 1.0f);
}
__device__ __forceinline__ float sigm_f(float x) {
    return __builtin_amdgcn_rcpf(1.0f + __expf(-x));
}

// ---------------- K0: fp32 -> fp16 cvt (vector4) ----------------
__global__ void cvt_f32_f16(const float* __restrict__ src,
                            _Float16* __restrict__ dst, int n4) {
    int i = blockIdx.x * blockDim.x + threadIdx.x;
    int stride = gridDim.x * blockDim.x;
    for (; i < n4; i += stride) {
        float4 v = ((const float4*)src)[i];
        f16x2 a; a.x = (_Float16)v.x; a.y = (_Float16)v.y;
        f16x2 b; b.x = (_Float16)v.z; b.y = (_Float16)v.w;
        ((f16x2*)dst)[2 * i]     = a;
        ((f16x2*)dst)[2 * i + 1] = b;
    }
}

// ---------------- KG: xg[M,512] = A[M,K] . W[512,K]^T + (bih+bhh) ----------
// Block: 256 thr = 4 waves; wave w owns m16 tile (blk*64 + w*16), all 32 n-tiles.
// MFMA 16x16x32 f16. A/B fragments are direct b128 global loads:
//   frag lane l: row (l&15), k = ks*32 + (l>>4)*8 .. +8  (contiguous fp16).
// C/D: col=lane&15, row=(lane>>4)*4+reg  [measured: learn_hip m89].
__global__ __launch_bounds__(256, 1) void gemm_xg(
    const _Float16* __restrict__ A, const _Float16* __restrict__ W,
    const float* __restrict__ bih, const float* __restrict__ bhh,
    _Float16* __restrict__ out, int K)
{
    const int l  = threadIdx.x & 63;
    const int w  = threadIdx.x >> 6;
    const int mb = blockIdx.x * 64 + w * 16;
    const int c  = l & 15;       // tile col (n) / frag row
    const int q  = l >> 4;       // quad

    __shared__ float biasl[512];
    for (int i = threadIdx.x; i < 512; i += 256) biasl[i] = bih[i] + bhh[i];
    __syncthreads();

    f32x4 C[32];
    #pragma unroll
    for (int i = 0; i < 32; ++i) C[i] = (f32x4){0.f, 0.f, 0.f, 0.f};

    const int nks = K >> 5;
    for (int ks = 0; ks < nks; ++ks) {
        f16x8 Af = *(const f16x8*)(A + (size_t)(mb + c) * K + ks * 32 + q * 8);
        #pragma unroll
        for (int nt = 0; nt < 32; ++nt) {
            f16x8 Bf = *(const f16x8*)(W + (size_t)(nt * 16 + c) * K + ks * 32 + q * 8);
            C[nt] = __builtin_amdgcn_mfma_f32_16x16x32_f16(Af, Bf, C[nt], 0, 0, 0);
        }
    }
    // epilogue: bias + cvt + fp16 stores (quad-contiguous 32B segments)
    #pragma unroll
    for (int nt = 0; nt < 32; ++nt) {
        float bv = biasl[nt * 16 + c];
        #pragma unroll
        for (int i = 0; i < 4; ++i) {
            int row = mb + q * 4 + i;
            out[(size_t)row * 512 + nt * 16 + c] = (_Float16)(C[nt][i] + bv);
        }
    }
}

// ---------------- KR: one recurrent layer (MFMA broadcast-row engine) -----
// 256 blocks (1 batch each) x 512 thr (8 waves). Wave w, lane l (c=l&15,
// q=l>>4) owns unit = w*16+c. B-frags (Whh rows g*128+unit, k-slice q*8)
// resident in 64 VGPRs. Per step:
//   acc[g] = splat((float)xg[b][step][g*128+unit])        (bias included)
//   for kt: Af = hbuf[cur][kt*32 + q*8 ..]  (quad-broadcast, all A rows = h)
//           acc[g] += Af @ Bf[g][kt]
//   all-lane redundant activations -> c,h; lanes<16 write hbuf[nxt][unit]
//   ONE __syncthreads per step.
// flags bit0: write h to h_out (layer0); bit1: final-step FC -> out (layer1)
__global__ __launch_bounds__(512, 1) void lstm_rec(
    const float* __restrict__ whh,      // [512,128] fp32
    const _Float16* __restrict__ xg,    // [B*T,512] fp16 (bias included)
    _Float16* __restrict__ h_out,       // [B*T,128] fp16
    const float* __restrict__ fc_w, const float* __restrict__ fc_b,
    float* __restrict__ out, int flags)
{
    const int t = threadIdx.x;
    const int b = blockIdx.x;
    const int w = t >> 6;        // wave 0..7
    const int l = t & 63;
    const int q = l >> 4;        // quad 0..3
    const int c = l & 15;
    const int unit = (w << 4) + c;   // 0..127

    __shared__ __align__(16) _Float16 hbuf[2][128];
    __shared__ float redbuf[128];

    // ---- resident Whh B-frags: rows g*128+unit, k = kt*32 + q*8 .. +8 ----
    f16x8 Bf[4][4];
    #pragma unroll
    for (int g = 0; g < 4; ++g) {
        #pragma unroll
        for (int kt = 0; kt < 4; ++kt) {
            const float* wp = whh + (size_t)((g << 7) + unit) * 128 + (kt << 5) + (q << 3);
            float4 v0 = ((const float4*)wp)[0];
            float4 v1 = ((const float4*)wp)[1];
            f16x8 f;
            f[0] = (_Float16)v0.x; f[1] = (_Float16)v0.y;
            f[2] = (_Float16)v0.z; f[3] = (_Float16)v0.w;
            f[4] = (_Float16)v1.x; f[5] = (_Float16)v1.y;
            f[6] = (_Float16)v1.z; f[7] = (_Float16)v1.w;
            Bf[g][kt] = f;
        }
    }

    if (t < 128) {
        hbuf[0][t] = (_Float16)0.f;
        hbuf[1][t] = (_Float16)0.f;
    }

    // ---- xg prefetch (depth 2): per-lane cols g*128+unit, one 32B seg/wave/g
    const _Float16* __restrict__ xgl = xg + (size_t)b * TT * 512 + unit;
    _Float16 xa[4], xb[4];
    #pragma unroll
    for (int g = 0; g < 4; ++g) {
        xa[g] = xgl[(g << 7)];
        xb[g] = xgl[512 + (g << 7)];
    }

    float cst = 0.f;   // cell state of `unit` (redundant across quads)
    __syncthreads();

    auto step = [&](int s, _Float16* xs) {
        // acc init: splat xg value (all rows equal -> all quads equal)
        f32x4 acc[4];
        #pragma unroll
        for (int g = 0; g < 4; ++g) {
            float xv = (float)xs[g];
            acc[g] = (f32x4){xv, xv, xv, xv};
        }
        // prefetch step s+2 (uniform branch)
        if (s + 2 < TT) {
            #pragma unroll
            for (int g = 0; g < 4; ++g)
                xs[g] = xgl[(size_t)(s + 2) * 512 + (g << 7)];
        }
        // MFMA: gates = h @ Whh^T, A rows broadcast from LDS
        const _Float16* hb = hbuf[s & 1];
        #pragma unroll
        for (int kt = 0; kt < 4; ++kt) {
            f16x8 Af = *(const f16x8*)(hb + (kt << 5) + (q << 3));
            #pragma unroll
            for (int g = 0; g < 4; ++g)
                acc[g] = __builtin_amdgcn_mfma_f32_16x16x32_f16(Af, Bf[g][kt], acc[g], 0, 0, 0);
        }
        // activations: lane holds full (i,f,g,o) quad of `unit` in acc[*][0]
        float gi = sigm_f(acc[0][0]);
        float gf = sigm_f(acc[1][0]);
        float gg = tanh_f(acc[2][0]);
        float go = sigm_f(acc[3][0]);
        cst = gf * cst + gi * gg;
        float hh = go * tanh_f(cst);
        _Float16 h16 = (_Float16)hh;
        if (l < 16) {
            hbuf[(s + 1) & 1][unit] = h16;
            if (flags & 1)
                h_out[((size_t)b * TT + s) * 128 + unit] = h16;
            if ((flags & 2) && s == TT - 1) redbuf[unit] = hh;
        }
        __syncthreads();   // h(s) visible for step s+1
    };

    #pragma unroll 1
    for (int s = 0; s < TT; s += 2) {
        step(s, xa);
        step(s + 1, xb);
    }

    if (flags & 2) {
        if (t < 64) {
            float p = redbuf[t] * fc_w[t] + redbuf[t + 64] * fc_w[t + 64];
            #pragma unroll
            for (int off = 32; off > 0; off >>= 1) p += __shfl_down(p, off, 64);
            if (t == 0) out[b] = p + fc_b[0];
        }
    }
}

extern "C" void kernel_launch(void* const* d_in, const int* in_sizes, int n_in,
                              void* d_out, int out_size, void* d_ws, size_t ws_size,
                              hipStream_t stream) {
    const float* x     = (const float*)d_in[0];
    const float* w_ih0 = (const float*)d_in[1];
    const float* w_hh0 = (const float*)d_in[2];
    const float* b_ih0 = (const float*)d_in[3];
    const float* b_hh0 = (const float*)d_in[4];
    const float* w_ih1 = (const float*)d_in[5];
    const float* w_hh1 = (const float*)d_in[6];
    const float* b_ih1 = (const float*)d_in[7];
    const float* b_hh1 = (const float*)d_in[8];
    const float* fc_w  = (const float*)d_in[9];
    const float* fc_b  = (const float*)d_in[10];
    float* out = (float*)d_out;

    // ws layout (bytes)
    char* ws = (char*)d_ws;
    _Float16* xg     = (_Float16*)(ws);                            // 134217728
    _Float16* h0_all = (_Float16*)(ws + 134217728);                //  33554432
    _Float16* x16    = (_Float16*)(ws + 134217728 + 33554432);     //  16777216
    _Float16* w0_16  = (_Float16*)(ws + 134217728 + 33554432 + 16777216);          // 65536
    _Float16* w1_16  = (_Float16*)(ws + 134217728 + 33554432 + 16777216 + 65536);  // 131072

    // K0: conversions
    cvt_f32_f16<<<dim3(1024), dim3(256), 0, stream>>>(x, x16, (256 * 512 * 64) / 4);
    cvt_f32_f16<<<dim3(32), dim3(256), 0, stream>>>(w_ih0, w0_16, (512 * 64) / 4);
    cvt_f32_f16<<<dim3(64), dim3(256), 0, stream>>>(w_ih1, w1_16, (512 * 128) / 4);

    // KG: xg0 = x16 . Wih0^T + (b_ih0 + b_hh0)
    gemm_xg<<<dim3(MM / 64), dim3(256), 0, stream>>>(x16, w0_16, b_ih0, b_hh0, xg, 64);

    // KR: layer 0 (writes h0_all)
    lstm_rec<<<dim3(256), dim3(512), 0, stream>>>(w_hh0, xg, h0_all,
                                                  fc_w, fc_b, out, 1);

    // KG: xg1 = h0_all . Wih1^T + (b_ih1 + b_hh1)  (reuses xg buffer)
    gemm_xg<<<dim3(MM / 64), dim3(256), 0, stream>>>(h0_all, w1_16, b_ih1, b_hh1, xg, 128);

    // KR: layer 1 (+ fused FC)
    lstm_rec<<<dim3(256), dim3(512), 0, stream>>>(w_hh1, xg, h0_all,
                                                  fc_w, fc_b, out, 2);
}

// Round 2
// 929.020 us; speedup vs baseline: 1.1498x; 1.1498x over previous
//
#include <hip/hip_runtime.h>
#include <hip/hip_fp16.h>

// LSTM B=256,T=512,IN=64,H=128,L=2 + FC.
//  K0 cvt       : x, w_ih0 -> fp16 (ws)
//  KG (MFMA)    : xg0 = x16.Wih0^T + bias   [131072,512] fp16 (ws)
//  KF (fused)   : BOTH recurrent layers pipelined + per-step xg1 GEMV + FC
//
// KF: 256 blocks x 512 thr (8 waves). Wave w, lane (q=l>>4, c=l&15) owns
// unit = w*16+c. Per iteration s (514 iters):
//   L0-rec : gates0(s)   = h0(s-1) @ Whh0^T + xg0[s]        (Whh0 in 64 VGPR)
//   xgate  : xg1(s-1)    = h0(s-1) @ Wih1^T + bias1         (Wih1 in LDS,
//            XOR-swizzled; shares A-frags with L0-rec; result kept in regs,
//            consumed NEXT iter -> latency-tolerant)
//   L1-rec : gates1(s-2) = h1(s-3) @ Whh1^T + xg1(s-2)      (Whh1 in 64 VGPR)
// 12 independent MFMA accumulator chains + 2 independent activation blocks
// per iter = real ILP inside the latency-bound step. One barrier per iter.
// h state in double-buffered 256B LDS; h0 never touches HBM; second GEMM
// dispatch eliminated. MFMA broadcast-row trick: all 16 A-rows = h, so lane
// (q,c) of wave w holds gate quad (i,f,g,o) of its unit in acc[g][0]; acc
// elements [1..3] are dead (init {v,0,0,0}).

#define TT 512
#define MM (256 * 512)   // 131072 rows for the batched GEMM

typedef _Float16 f16x2 __attribute__((ext_vector_type(2)));
typedef _Float16 f16x8 __attribute__((ext_vector_type(8)));
typedef float f32x4 __attribute__((ext_vector_type(4)));

__device__ __forceinline__ float tanh_f(float x) {
    float e = __expf(2.0f * x);
    return 1.0f - 2.0f * __builtin_amdgcn_rcpf(e + 1.0f);
}
__device__ __forceinline__ float sigm_f(float x) {
    return __builtin_amdgcn_rcpf(1.0f + __expf(-x));
}

// ---------------- K0: fp32 -> fp16 cvt (vector4) ----------------
__global__ void cvt_f32_f16(const float* __restrict__ src,
                            _Float16* __restrict__ dst, int n4) {
    int i = blockIdx.x * blockDim.x + threadIdx.x;
    int stride = gridDim.x * blockDim.x;
    for (; i < n4; i += stride) {
        float4 v = ((const float4*)src)[i];
        f16x2 a; a.x = (_Float16)v.x; a.y = (_Float16)v.y;
        f16x2 b; b.x = (_Float16)v.z; b.y = (_Float16)v.w;
        ((f16x2*)dst)[2 * i]     = a;
        ((f16x2*)dst)[2 * i + 1] = b;
    }
}

// ---------------- KG: xg[M,512] = A[M,K] . W[512,K]^T + (bih+bhh) ----------
__global__ __launch_bounds__(256, 1) void gemm_xg(
    const _Float16* __restrict__ A, const _Float16* __restrict__ W,
    const float* __restrict__ bih, const float* __restrict__ bhh,
    _Float16* __restrict__ out, int K)
{
    const int l  = threadIdx.x & 63;
    const int w  = threadIdx.x >> 6;
    const int mb = blockIdx.x * 64 + w * 16;
    const int c  = l & 15;       // tile col (n) / frag row
    const int q  = l >> 4;       // quad

    __shared__ float biasl[512];
    for (int i = threadIdx.x; i < 512; i += 256) biasl[i] = bih[i] + bhh[i];
    __syncthreads();

    f32x4 C[32];
    #pragma unroll
    for (int i = 0; i < 32; ++i) C[i] = (f32x4){0.f, 0.f, 0.f, 0.f};

    const int nks = K >> 5;
    for (int ks = 0; ks < nks; ++ks) {
        f16x8 Af = *(const f16x8*)(A + (size_t)(mb + c) * K + ks * 32 + q * 8);
        #pragma unroll
        for (int nt = 0; nt < 32; ++nt) {
            f16x8 Bf = *(const f16x8*)(W + (size_t)(nt * 16 + c) * K + ks * 32 + q * 8);
            C[nt] = __builtin_amdgcn_mfma_f32_16x16x32_f16(Af, Bf, C[nt], 0, 0, 0);
        }
    }
    #pragma unroll
    for (int nt = 0; nt < 32; ++nt) {
        float bv = biasl[nt * 16 + c];
        #pragma unroll
        for (int i = 0; i < 4; ++i) {
            int row = mb + q * 4 + i;
            out[(size_t)row * 512 + nt * 16 + c] = (_Float16)(C[nt][i] + bv);
        }
    }
}

// ---------------- KF: fused two-layer recurrence + FC ----------------
__global__ __launch_bounds__(512, 1) void lstm_fused(
    const float* __restrict__ whh0, const float* __restrict__ wih1,
    const float* __restrict__ whh1,
    const float* __restrict__ bih1, const float* __restrict__ bhh1,
    const _Float16* __restrict__ xg0,   // [B*T,512] fp16 (bias included)
    const float* __restrict__ fc_w, const float* __restrict__ fc_b,
    float* __restrict__ out)
{
    const int t = threadIdx.x;
    const int b = blockIdx.x;
    const int w = t >> 6;
    const int l = t & 63;
    const int q = l >> 4;        // quad 0..3
    const int c = l & 15;
    const int unit = (w << 4) + c;   // 0..127

    // Wih1 as fp16 in LDS, XOR-swizzled on 16B chunks: chunk j of row r
    // stored at chunk (j ^ (r&7)).  Frag read => 2 lanes/bank (free).
    __shared__ __align__(16) _Float16 w1lds[512 * 128];
    __shared__ __align__(16) _Float16 h0buf[2][128];
    __shared__ __align__(16) _Float16 h1buf[2][128];
    __shared__ float redbuf[128];

    // ---- stage Wih1 -> LDS (one row per thread, cvt + swizzle) ----
    {
        const int r = t;
        const float* src = wih1 + (size_t)r * 128;
        #pragma unroll
        for (int j = 0; j < 16; ++j) {
            float4 v0 = ((const float4*)src)[2 * j];
            float4 v1 = ((const float4*)src)[2 * j + 1];
            f16x8 f;
            f[0] = (_Float16)v0.x; f[1] = (_Float16)v0.y;
            f[2] = (_Float16)v0.z; f[3] = (_Float16)v0.w;
            f[4] = (_Float16)v1.x; f[5] = (_Float16)v1.y;
            f[6] = (_Float16)v1.z; f[7] = (_Float16)v1.w;
            *(f16x8*)&w1lds[r * 128 + ((j ^ (r & 7)) << 3)] = f;
        }
    }

    // ---- resident B-frags: Whh0, Whh1 rows g*128+unit, k = kt*32+q*8 ----
    f16x8 B0[4][4], B1[4][4];
    #pragma unroll
    for (int g = 0; g < 4; ++g) {
        #pragma unroll
        for (int kt = 0; kt < 4; ++kt) {
            const size_t off = (size_t)((g << 7) + unit) * 128 + (kt << 5) + (q << 3);
            {
                float4 v0 = ((const float4*)(whh0 + off))[0];
                float4 v1 = ((const float4*)(whh0 + off))[1];
                f16x8 f;
                f[0] = (_Float16)v0.x; f[1] = (_Float16)v0.y;
                f[2] = (_Float16)v0.z; f[3] = (_Float16)v0.w;
                f[4] = (_Float16)v1.x; f[5] = (_Float16)v1.y;
                f[6] = (_Float16)v1.z; f[7] = (_Float16)v1.w;
                B0[g][kt] = f;
            }
            {
                float4 v0 = ((const float4*)(whh1 + off))[0];
                float4 v1 = ((const float4*)(whh1 + off))[1];
                f16x8 f;
                f[0] = (_Float16)v0.x; f[1] = (_Float16)v0.y;
                f[2] = (_Float16)v0.z; f[3] = (_Float16)v0.w;
                f[4] = (_Float16)v1.x; f[5] = (_Float16)v1.y;
                f[6] = (_Float16)v1.z; f[7] = (_Float16)v1.w;
                B1[g][kt] = f;
            }
        }
    }

    float bias1v[4];
    #pragma unroll
    for (int g = 0; g < 4; ++g)
        bias1v[g] = bih1[(g << 7) + unit] + bhh1[(g << 7) + unit];

    if (t < 128) {
        h0buf[0][t] = (_Float16)0.f; h0buf[1][t] = (_Float16)0.f;
        h1buf[0][t] = (_Float16)0.f; h1buf[1][t] = (_Float16)0.f;
    }

    // ---- xg0 prefetch (depth 2) ----
    const _Float16* __restrict__ xgl = xg0 + (size_t)b * TT * 512 + unit;
    _Float16 xa[4], xb[4];
    #pragma unroll
    for (int g = 0; g < 4; ++g) {
        xa[g] = xgl[(g << 7)];
        xb[g] = xgl[512 + (g << 7)];
    }

    float xgA[4] = {0.f, 0.f, 0.f, 0.f};   // xg1 of even steps
    float xgB[4] = {0.f, 0.f, 0.f, 0.f};   // xg1 of odd steps
    float cst0 = 0.f, cst1 = 0.f;
    __syncthreads();

    // Pipeline at iter s: L0 step s | xgate step s-1 | L1 step s-2.
    auto step = [&](int s, _Float16* xs, float* xgc, float* xgp) {
        const _Float16* h0r = h0buf[(s + 1) & 1];   // h0(s-1)
        const _Float16* h1r = h1buf[(s + 1) & 1];   // h1(s-3)
        f16x8 Af0[4];
        #pragma unroll
        for (int kt = 0; kt < 4; ++kt)
            Af0[kt] = *(const f16x8*)(h0r + (kt << 5) + (q << 3));

        f32x4 a0[4], a1[4], xx[4];
        #pragma unroll
        for (int g = 0; g < 4; ++g) {
            a0[g] = (f32x4){(float)xs[g], 0.f, 0.f, 0.f};
            a1[g] = (f32x4){xgc[g],       0.f, 0.f, 0.f};
            xx[g] = (f32x4){bias1v[g],    0.f, 0.f, 0.f};
        }
        if (s + 2 < TT) {   // prefetch xg0 for step s+2
            #pragma unroll
            for (int g = 0; g < 4; ++g)
                xs[g] = xgl[(size_t)(s + 2) * 512 + (g << 7)];
        }

        // L0-rec + L1-rec: 8 independent accumulator chains per kt group
        #pragma unroll
        for (int kt = 0; kt < 4; ++kt) {
            f16x8 Af1 = *(const f16x8*)(h1r + (kt << 5) + (q << 3));
            #pragma unroll
            for (int g = 0; g < 4; ++g)
                a0[g] = __builtin_amdgcn_mfma_f32_16x16x32_f16(Af0[kt], B0[g][kt], a0[g], 0, 0, 0);
            #pragma unroll
            for (int g = 0; g < 4; ++g)
                a1[g] = __builtin_amdgcn_mfma_f32_16x16x32_f16(Af1, B1[g][kt], a1[g], 0, 0, 0);
        }
        // xgate: xg1(s-1) = h0(s-1) @ Wih1^T + bias1  (Wih1 frags from LDS)
        #pragma unroll
        for (int kt = 0; kt < 4; ++kt) {
            #pragma unroll
            for (int g = 0; g < 4; ++g) {
                const int row = (g << 7) + unit;
                f16x8 Wf = *(const f16x8*)&w1lds[row * 128 +
                              ((((kt << 2) + q) ^ (c & 7)) << 3)];
                xx[g] = __builtin_amdgcn_mfma_f32_16x16x32_f16(Af0[kt], Wf, xx[g], 0, 0, 0);
            }
        }

        // L0 activation (uniform guard)
        if (s < TT) {
            float gi = sigm_f(a0[0][0]);
            float gf = sigm_f(a0[1][0]);
            float gg = tanh_f(a0[2][0]);
            float go = sigm_f(a0[3][0]);
            cst0 = gf * cst0 + gi * gg;
            float hh = go * tanh_f(cst0);
            if (l < 16) h0buf[s & 1][unit] = (_Float16)hh;
        }
        // L1 activation for step s-2 (uniform guard)
        if (s >= 2) {
            float gi = sigm_f(a1[0][0]);
            float gf = sigm_f(a1[1][0]);
            float gg = tanh_f(a1[2][0]);
            float go = sigm_f(a1[3][0]);
            cst1 = gf * cst1 + gi * gg;
            float hh = go * tanh_f(cst1);
            if (l < 16) {
                h1buf[s & 1][unit] = (_Float16)hh;
                if (s == TT + 1) redbuf[unit] = hh;
            }
        }
        #pragma unroll
        for (int g = 0; g < 4; ++g) xgp[g] = xx[g][0];
        __syncthreads();
    };

    #pragma unroll 1
    for (int s = 0; s < TT + 2; s += 2) {
        step(s,     xa, xgA, xgB);
        step(s + 1, xb, xgB, xgA);
    }

    // fused FC on h1(T-1)
    if (t < 64) {
        float p = redbuf[t] * fc_w[t] + redbuf[t + 64] * fc_w[t + 64];
        #pragma unroll
        for (int off = 32; off > 0; off >>= 1) p += __shfl_down(p, off, 64);
        if (t == 0) out[b] = p + fc_b[0];
    }
}

extern "C" void kernel_launch(void* const* d_in, const int* in_sizes, int n_in,
                              void* d_out, int out_size, void* d_ws, size_t ws_size,
                              hipStream_t stream) {
    const float* x     = (const float*)d_in[0];
    const float* w_ih0 = (const float*)d_in[1];
    const float* w_hh0 = (const float*)d_in[2];
    const float* b_ih0 = (const float*)d_in[3];
    const float* b_hh0 = (const float*)d_in[4];
    const float* w_ih1 = (const float*)d_in[5];
    const float* w_hh1 = (const float*)d_in[6];
    const float* b_ih1 = (const float*)d_in[7];
    const float* b_hh1 = (const float*)d_in[8];
    const float* fc_w  = (const float*)d_in[9];
    const float* fc_b  = (const float*)d_in[10];
    float* out = (float*)d_out;

    // ws layout (bytes)
    char* ws = (char*)d_ws;
    _Float16* xg    = (_Float16*)(ws);                         // 134217728
    _Float16* x16   = (_Float16*)(ws + 134217728);             //  16777216
    _Float16* w0_16 = (_Float16*)(ws + 134217728 + 16777216);  //  65536

    // K0: conversions
    cvt_f32_f16<<<dim3(1024), dim3(256), 0, stream>>>(x, x16, (256 * 512 * 64) / 4);
    cvt_f32_f16<<<dim3(32), dim3(256), 0, stream>>>(w_ih0, w0_16, (512 * 64) / 4);

    // KG: xg0 = x16 . Wih0^T + (b_ih0 + b_hh0)
    gemm_xg<<<dim3(MM / 64), dim3(256), 0, stream>>>(x16, w0_16, b_ih0, b_hh0, xg, 64);

    // KF: both layers + FC
    lstm_fused<<<dim3(256), dim3(512), 0, stream>>>(w_hh0, w_ih1, w_hh1,
                                                    b_ih1, b_hh1, xg,
                                                    fc_w, fc_b, out);
}

// Round 3
// 746.261 us; speedup vs baseline: 1.4314x; 1.2449x over previous
//
#include <hip/hip_runtime.h>
#include <hip/hip_fp16.h>

// LSTM B=256,T=512,IN=64,H=128,L=2 + FC.
//  K0 cvt       : x, w_ih0 -> fp16 (ws)
//  KG (MFMA)    : xg0 = x16.Wih0^T + bias -> [B*T][unit][4g] interleaved fp16
//  KF (fused)   : both recurrent layers, chunk-pipelined, + chunked xgate
//                 GEMM + fused FC
//
// KF v3: L1 lags L0 by CH=16 steps. Per iteration (528 total):
//   L0-rec : gates0(s)    = h0(s-1) @ Whh0^T + xg0[s]   (Whh0 in 64 VGPR)
//   L1-rec : gates1(s-16) = h1(s-17) @ Whh1^T + xg1[s-16] (Whh1 in 64 VGPR)
// h0 rows accumulate in h0tile[16][128] (XOR-swizzled 16B chunks). Every 16
// iters, a GEMM phase computes xg1tile[16][512] = h0tile @ Wih1^T + b1 as a
// REAL 16-row MFMA GEMM (16 MFMA/wave per chunk vs v2's 16/step): Wih1 is
// read from LDS once per chunk (8KB/step amortized) instead of once per step
// (128KB/step). Per-iter: 32 MFMA/wave, ~1KB LDS traffic, 1 barrier.
// Broadcast-row MFMA trick for the recurrences: all 16 A-rows = h, lane
// (q,c) of wave w holds gate quad of unit w*16+c in acc[g][0].

#define TT 512
#define CH 16
#define NCH 32            // TT / CH
#define MM (256 * 512)    // 131072 rows for the batched GEMM

typedef _Float16 f16x2 __attribute__((ext_vector_type(2)));
typedef _Float16 f16x4 __attribute__((ext_vector_type(4)));
typedef _Float16 f16x8 __attribute__((ext_vector_type(8)));
typedef float f32x4 __attribute__((ext_vector_type(4)));

__device__ __forceinline__ float tanh_f(float x) {
    float e = __expf(2.0f * x);
    return 1.0f - 2.0f * __builtin_amdgcn_rcpf(e + 1.0f);
}
__device__ __forceinline__ float sigm_f(float x) {
    return __builtin_amdgcn_rcpf(1.0f + __expf(-x));
}

// ---------------- K0: fp32 -> fp16 cvt (vector4) ----------------
__global__ void cvt_f32_f16(const float* __restrict__ src,
                            _Float16* __restrict__ dst, int n4) {
    int i = blockIdx.x * blockDim.x + threadIdx.x;
    int stride = gridDim.x * blockDim.x;
    for (; i < n4; i += stride) {
        float4 v = ((const float4*)src)[i];
        f16x2 a; a.x = (_Float16)v.x; a.y = (_Float16)v.y;
        f16x2 b; b.x = (_Float16)v.z; b.y = (_Float16)v.w;
        ((f16x2*)dst)[2 * i]     = a;
        ((f16x2*)dst)[2 * i + 1] = b;
    }
}

// ---------------- KG: xg[M,512] = A[M,K] . W[512,K]^T + (bih+bhh) ----------
// Output layout INTERLEAVED: out[row][unit][gate] (f16x4 per unit) so the
// recurrent kernel loads one 8B f16x4 per lane per step.
__global__ __launch_bounds__(256, 1) void gemm_xg(
    const _Float16* __restrict__ A, const _Float16* __restrict__ W,
    const float* __restrict__ bih, const float* __restrict__ bhh,
    _Float16* __restrict__ out, int K)
{
    const int l  = threadIdx.x & 63;
    const int w  = threadIdx.x >> 6;
    const int mb = blockIdx.x * 64 + w * 16;
    const int c  = l & 15;       // tile col (n) / frag row
    const int q  = l >> 4;       // quad

    __shared__ float biasl[512];
    for (int i = threadIdx.x; i < 512; i += 256) biasl[i] = bih[i] + bhh[i];
    __syncthreads();

    f32x4 C[32];
    #pragma unroll
    for (int i = 0; i < 32; ++i) C[i] = (f32x4){0.f, 0.f, 0.f, 0.f};

    const int nks = K >> 5;
    for (int ks = 0; ks < nks; ++ks) {
        f16x8 Af = *(const f16x8*)(A + (size_t)(mb + c) * K + ks * 32 + q * 8);
        #pragma unroll
        for (int nt = 0; nt < 32; ++nt) {
            f16x8 Bf = *(const f16x8*)(W + (size_t)(nt * 16 + c) * K + ks * 32 + q * 8);
            C[nt] = __builtin_amdgcn_mfma_f32_16x16x32_f16(Af, Bf, C[nt], 0, 0, 0);
        }
    }
    #pragma unroll
    for (int nt = 0; nt < 32; ++nt) {
        float bv = biasl[nt * 16 + c];
        const int g = nt >> 3;
        const int u = ((nt & 7) << 4) + c;
        #pragma unroll
        for (int i = 0; i < 4; ++i) {
            int row = mb + q * 4 + i;
            out[(size_t)row * 512 + (u << 2) + g] = (_Float16)(C[nt][i] + bv);
        }
    }
}

// ---------------- KF: fused two-layer recurrence + chunked xgate + FC -----
__global__ __launch_bounds__(512, 1) void lstm_fused(
    const float* __restrict__ whh0, const float* __restrict__ wih1,
    const float* __restrict__ whh1,
    const float* __restrict__ bih1, const float* __restrict__ bhh1,
    const _Float16* __restrict__ xg0,   // [B*T][unit][4g] fp16 (bias incl.)
    const float* __restrict__ fc_w, const float* __restrict__ fc_b,
    float* __restrict__ out)
{
    const int t = threadIdx.x;
    const int b = blockIdx.x;
    const int w = t >> 6;
    const int l = t & 63;
    const int q = l >> 4;        // quad 0..3
    const int c = l & 15;
    const int unit = (w << 4) + c;   // 0..127

    // Wih1 fp16 in LDS, chunk-XOR swizzle: 16B chunk j of row r at j^(r&7).
    __shared__ __align__(16) _Float16 w1lds[512 * 128];        // 128 KB
    // h0 rows of the current chunk, chunk-XOR swizzled the same way.
    __shared__ __align__(16) _Float16 h0tile[CH * 128];        //   4 KB
    __shared__ __align__(16) _Float16 h1buf[2][128];           //  512 B
    // xg1 of the chunk being consumed: [time][unit][gate] f16x4 per unit.
    __shared__ __align__(16) _Float16 xg1t[CH * 128 * 4];      //  16 KB
    __shared__ float redbuf[128];

    // ---- stage Wih1 -> LDS (one row per thread, cvt + swizzle) ----
    {
        const int r = t;
        const float* src = wih1 + (size_t)r * 128;
        #pragma unroll
        for (int j = 0; j < 16; ++j) {
            float4 v0 = ((const float4*)src)[2 * j];
            float4 v1 = ((const float4*)src)[2 * j + 1];
            f16x8 f;
            f[0] = (_Float16)v0.x; f[1] = (_Float16)v0.y;
            f[2] = (_Float16)v0.z; f[3] = (_Float16)v0.w;
            f[4] = (_Float16)v1.x; f[5] = (_Float16)v1.y;
            f[6] = (_Float16)v1.z; f[7] = (_Float16)v1.w;
            *(f16x8*)&w1lds[r * 128 + ((j ^ (r & 7)) << 3)] = f;
        }
    }

    // ---- resident B-frags: Whh0, Whh1 rows g*128+unit, k = kt*32+q*8 ----
    f16x8 B0[4][4], B1[4][4];
    #pragma unroll
    for (int g = 0; g < 4; ++g) {
        #pragma unroll
        for (int kt = 0; kt < 4; ++kt) {
            const size_t off = (size_t)((g << 7) + unit) * 128 + (kt << 5) + (q << 3);
            {
                float4 v0 = ((const float4*)(whh0 + off))[0];
                float4 v1 = ((const float4*)(whh0 + off))[1];
                f16x8 f;
                f[0] = (_Float16)v0.x; f[1] = (_Float16)v0.y;
                f[2] = (_Float16)v0.z; f[3] = (_Float16)v0.w;
                f[4] = (_Float16)v1.x; f[5] = (_Float16)v1.y;
                f[6] = (_Float16)v1.z; f[7] = (_Float16)v1.w;
                B0[g][kt] = f;
            }
            {
                float4 v0 = ((const float4*)(whh1 + off))[0];
                float4 v1 = ((const float4*)(whh1 + off))[1];
                f16x8 f;
                f[0] = (_Float16)v0.x; f[1] = (_Float16)v0.y;
                f[2] = (_Float16)v0.z; f[3] = (_Float16)v0.w;
                f[4] = (_Float16)v1.x; f[5] = (_Float16)v1.y;
                f[6] = (_Float16)v1.z; f[7] = (_Float16)v1.w;
                B1[g][kt] = f;
            }
        }
    }

    // bias for the xgate GEMM phase: wave w owns n-tiles nt = w*4+i,
    // lane col c -> weight row nt*16+c.
    float bias1g[4];
    #pragma unroll
    for (int i = 0; i < 4; ++i) {
        const int r = (w * 4 + i) * 16 + c;
        bias1g[i] = bih1[r] + bhh1[r];
    }

    // init state: h1(-1)=0, h0(-1)=0 in ring slot 15 (swizzled).
    if (t < 128) {
        h1buf[0][t] = (_Float16)0.f;
        h1buf[1][t] = (_Float16)0.f;
        const int u = t, r = CH - 1;
        h0tile[r * 128 + ((((u >> 3) ^ (r & 7)) << 3) | (u & 7))] = (_Float16)0.f;
    }

    // xg0 prefetch (depth 2): one f16x4 per lane per step.
    const f16x4* __restrict__ xgl = (const f16x4*)xg0 + (size_t)b * TT * 128 + unit;
    f16x4 xa = xgl[0];
    f16x4 xb = xgl[128];

    float cst0 = 0.f, cst1 = 0.f;
    __syncthreads();

    // Per iteration: L0 step s0 = k*16+j, L1 step s1 = (k-1)*16+j.
    auto iter = [&](int k, int j, f16x4& xs, bool doL0, bool doL1) {
        const int s0 = k * CH + j;
        const int rp = (j + CH - 1) & (CH - 1);   // (j-1) & 15
        f16x8 Af0[4], Af1[4];
        if (doL0) {
            #pragma unroll
            for (int kt = 0; kt < 4; ++kt)
                Af0[kt] = *(const f16x8*)&h0tile[rp * 128 +
                             ((((kt << 2) + q) ^ (rp & 7)) << 3)];
        }
        if (doL1) {
            const _Float16* h1r = h1buf[(j & 1) ^ 1];
            #pragma unroll
            for (int kt = 0; kt < 4; ++kt)
                Af1[kt] = *(const f16x8*)&h1r[(kt << 5) + (q << 3)];
        }
        f16x4 xg1v;
        if (doL1) xg1v = *(const f16x4*)&xg1t[((j << 7) + unit) << 2];

        f32x4 a0[4], a1[4];
        #pragma unroll
        for (int g = 0; g < 4; ++g) {
            if (doL0) a0[g] = (f32x4){doL0 ? (float)xs[g] : 0.f, 0.f, 0.f, 0.f};
            if (doL1) a1[g] = (f32x4){(float)xg1v[g], 0.f, 0.f, 0.f};
        }
        if (doL0 && s0 + 2 < TT) xs = xgl[(size_t)(s0 + 2) * 128];

        #pragma unroll
        for (int kt = 0; kt < 4; ++kt) {
            if (doL0) {
                #pragma unroll
                for (int g = 0; g < 4; ++g)
                    a0[g] = __builtin_amdgcn_mfma_f32_16x16x32_f16(Af0[kt], B0[g][kt], a0[g], 0, 0, 0);
            }
            if (doL1) {
                #pragma unroll
                for (int g = 0; g < 4; ++g)
                    a1[g] = __builtin_amdgcn_mfma_f32_16x16x32_f16(Af1[kt], B1[g][kt], a1[g], 0, 0, 0);
            }
        }

        if (doL0) {
            float gi = sigm_f(a0[0][0]);
            float gf = sigm_f(a0[1][0]);
            float gg = tanh_f(a0[2][0]);
            float go = sigm_f(a0[3][0]);
            cst0 = gf * cst0 + gi * gg;
            float hh = go * tanh_f(cst0);
            if (l < 16)
                h0tile[j * 128 + ((((unit >> 3) ^ (j & 7)) << 3) | (unit & 7))] =
                    (_Float16)hh;
        }
        if (doL1) {
            float gi = sigm_f(a1[0][0]);
            float gf = sigm_f(a1[1][0]);
            float gg = tanh_f(a1[2][0]);
            float go = sigm_f(a1[3][0]);
            cst1 = gf * cst1 + gi * gg;
            float hh = go * tanh_f(cst1);
            if (l < 16) {
                h1buf[j & 1][unit] = (_Float16)hh;
                if (k == NCH && j == CH - 1) redbuf[unit] = hh;
            }
        }
        __syncthreads();
    };

    #pragma unroll 1
    for (int k = 0; k <= NCH; ++k) {
        const bool doL0 = (k < NCH);
        const bool doL1 = (k > 0);
        #pragma unroll 1
        for (int j = 0; j < CH; j += 2) {
            iter(k, j,     xa, doL0, doL1);
            iter(k, j + 1, xb, doL0, doL1);
        }
        // ---- xgate GEMM phase: xg1t = h0tile @ Wih1^T + b1 ----
        if (doL0) {
            f32x4 G[4];
            #pragma unroll
            for (int i = 0; i < 4; ++i)
                G[i] = (f32x4){bias1g[i], bias1g[i], bias1g[i], bias1g[i]};
            #pragma unroll
            for (int kt = 0; kt < 4; ++kt) {
                // A row = timestep c, original k-chunk (kt*4+q), swizzled.
                f16x8 Ag = *(const f16x8*)&h0tile[c * 128 +
                               ((((kt << 2) + q) ^ (c & 7)) << 3)];
                #pragma unroll
                for (int i = 0; i < 4; ++i) {
                    const int r = (w * 4 + i) * 16 + c;   // weight row
                    f16x8 Bg = *(const f16x8*)&w1lds[r * 128 +
                                   ((((kt << 2) + q) ^ (r & 7)) << 3)];
                    G[i] = __builtin_amdgcn_mfma_f32_16x16x32_f16(Ag, Bg, G[i], 0, 0, 0);
                }
            }
            // write xg1t[time][unit][gate]; D row = q*4+i2 (time), col c.
            #pragma unroll
            for (int i = 0; i < 4; ++i) {
                const int nt = w * 4 + i;
                const int g = nt >> 3;
                const int u = ((nt & 7) << 4) + c;
                #pragma unroll
                for (int i2 = 0; i2 < 4; ++i2)
                    xg1t[((((q << 2) + i2) << 7) + u) * 4 + g] = (_Float16)G[i][i2];
            }
            __syncthreads();
        }
    }

    // fused FC on h1(T-1)
    if (t < 64) {
        float p = redbuf[t] * fc_w[t] + redbuf[t + 64] * fc_w[t + 64];
        #pragma unroll
        for (int off = 32; off > 0; off >>= 1) p += __shfl_down(p, off, 64);
        if (t == 0) out[b] = p + fc_b[0];
    }
}

extern "C" void kernel_launch(void* const* d_in, const int* in_sizes, int n_in,
                              void* d_out, int out_size, void* d_ws, size_t ws_size,
                              hipStream_t stream) {
    const float* x     = (const float*)d_in[0];
    const float* w_ih0 = (const float*)d_in[1];
    const float* w_hh0 = (const float*)d_in[2];
    const float* b_ih0 = (const float*)d_in[3];
    const float* b_hh0 = (const float*)d_in[4];
    const float* w_ih1 = (const float*)d_in[5];
    const float* w_hh1 = (const float*)d_in[6];
    const float* b_ih1 = (const float*)d_in[7];
    const float* b_hh1 = (const float*)d_in[8];
    const float* fc_w  = (const float*)d_in[9];
    const float* fc_b  = (const float*)d_in[10];
    float* out = (float*)d_out;

    // ws layout (bytes)
    char* ws = (char*)d_ws;
    _Float16* xg    = (_Float16*)(ws);                         // 134217728
    _Float16* x16   = (_Float16*)(ws + 134217728);             //  16777216
    _Float16* w0_16 = (_Float16*)(ws + 134217728 + 16777216);  //  65536

    // K0: conversions
    cvt_f32_f16<<<dim3(1024), dim3(256), 0, stream>>>(x, x16, (256 * 512 * 64) / 4);
    cvt_f32_f16<<<dim3(32), dim3(256), 0, stream>>>(w_ih0, w0_16, (512 * 64) / 4);

    // KG: xg0 = x16 . Wih0^T + (b_ih0 + b_hh0), interleaved output
    gemm_xg<<<dim3(MM / 64), dim3(256), 0, stream>>>(x16, w0_16, b_ih0, b_hh0, xg, 64);

    // KF: both layers + chunked xgate + FC
    lstm_fused<<<dim3(256), dim3(512), 0, stream>>>(w_hh0, w_ih1, w_hh1,
                                                    b_ih1, b_hh1, xg,
                                                    fc_w, fc_b, out);
}

// Round 4
// 619.680 us; speedup vs baseline: 1.7238x; 1.2043x over previous
//
#include <hip/hip_runtime.h>
#include <hip/hip_fp16.h>

// LSTM B=256,T=512,IN=64,H=128,L=2 + FC.
//  K0 cvt       : w_ih0 -> fp16 (tiny)
//  KG (MFMA)    : xg0 = x(f32).Wih0^T + bias -> [B*T][unit][4g] f16 (fused cvt)
//  KF (fused)   : both recurrent layers (L1 lags 16 steps) + chunked xgate
//                 GEMM + fused FC
//
// KF v4: fully-unrolled 16-step chunk body. All LDS ops = loop-invariant
// vaddr + compile-time immediates (j/rp/kt/buffer-select static). h0tile
// UNswizzled, row-padded to 136 elems (272B): recurrent A-frag reads are
// quad-broadcast (conflict-free by construction); phase's row-strided reads
// land 2-way (free). Stale-acc trick: MFMA D[i]=A.B+C[i] elementwise, only
// [0] is read, so acc[g][1..3] stay stale forever (no re-init movs).
// Uniform pipeline: k=0 runs L1 on zeroed xg1t/h1buf (exact zero-dynamics),
// k=NCH runs L0 on harmless garbage -> no per-iter predication.
// Phase: wave w owns tiles {g*8+w}, lane holds all 4 gates of unit w*16+c
// -> packed f16x4 xg1t writes, bias folded in.

#define TT 512
#define CH 16
#define NCH 32            // TT / CH
#define MM (256 * 512)    // 131072 rows for the batched GEMM
#define HP 136            // padded h0tile row stride (elems)

typedef _Float16 f16x2 __attribute__((ext_vector_type(2)));
typedef _Float16 f16x4 __attribute__((ext_vector_type(4)));
typedef _Float16 f16x8 __attribute__((ext_vector_type(8)));
typedef float f32x4 __attribute__((ext_vector_type(4)));

__device__ __forceinline__ float tanh_f(float x) {
    float e = __expf(2.0f * x);
    return 1.0f - 2.0f * __builtin_amdgcn_rcpf(e + 1.0f);
}
__device__ __forceinline__ float sigm_f(float x) {
    return __builtin_amdgcn_rcpf(1.0f + __expf(-x));
}

// ---------------- K0: fp32 -> fp16 cvt (vector4) ----------------
__global__ void cvt_f32_f16(const float* __restrict__ src,
                            _Float16* __restrict__ dst, int n4) {
    int i = blockIdx.x * blockDim.x + threadIdx.x;
    int stride = gridDim.x * blockDim.x;
    for (; i < n4; i += stride) {
        float4 v = ((const float4*)src)[i];
        f16x2 a; a.x = (_Float16)v.x; a.y = (_Float16)v.y;
        f16x2 b; b.x = (_Float16)v.z; b.y = (_Float16)v.w;
        ((f16x2*)dst)[2 * i]     = a;
        ((f16x2*)dst)[2 * i + 1] = b;
    }
}

// ------- KG: xg[M][u][4g] = A32[M,64] . W[512,64]^T + (bih+bhh) ----------
// A read as f32 (fused cvt). Output packed f16x4 per unit (gate-major regs).
__global__ __launch_bounds__(256, 1) void gemm_xg0(
    const float* __restrict__ A32, const _Float16* __restrict__ W,
    const float* __restrict__ bih, const float* __restrict__ bhh,
    _Float16* __restrict__ out)
{
    const int l  = threadIdx.x & 63;
    const int w  = threadIdx.x >> 6;
    const int mb = blockIdx.x * 64 + w * 16;
    const int c  = l & 15;       // tile col (n) / frag row
    const int q  = l >> 4;       // quad

    __shared__ float biasl[512];
    for (int i = threadIdx.x; i < 512; i += 256) biasl[i] = bih[i] + bhh[i];
    __syncthreads();

    f32x4 C[32];
    #pragma unroll
    for (int i = 0; i < 32; ++i) C[i] = (f32x4){0.f, 0.f, 0.f, 0.f};

    #pragma unroll
    for (int ks = 0; ks < 2; ++ks) {
        const float* ap = A32 + (size_t)(mb + c) * 64 + ks * 32 + q * 8;
        float4 v0 = ((const float4*)ap)[0];
        float4 v1 = ((const float4*)ap)[1];
        f16x8 Af;
        Af[0] = (_Float16)v0.x; Af[1] = (_Float16)v0.y;
        Af[2] = (_Float16)v0.z; Af[3] = (_Float16)v0.w;
        Af[4] = (_Float16)v1.x; Af[5] = (_Float16)v1.y;
        Af[6] = (_Float16)v1.z; Af[7] = (_Float16)v1.w;
        #pragma unroll
        for (int nt = 0; nt < 32; ++nt) {
            f16x8 Bf = *(const f16x8*)(W + (size_t)(nt * 16 + c) * 64 + ks * 32 + q * 8);
            C[nt] = __builtin_amdgcn_mfma_f32_16x16x32_f16(Af, Bf, C[nt], 0, 0, 0);
        }
    }
    // epilogue: gate-packed f16x4 stores (8B/lane, 128B contiguous per row)
    #pragma unroll
    for (int uu = 0; uu < 8; ++uu) {
        float b0 = biasl[uu * 16 + c];
        float b1 = biasl[128 + uu * 16 + c];
        float b2 = biasl[256 + uu * 16 + c];
        float b3 = biasl[384 + uu * 16 + c];
        #pragma unroll
        for (int i = 0; i < 4; ++i) {
            int row = mb + q * 4 + i;
            f16x4 pk;
            pk[0] = (_Float16)(C[uu][i]      + b0);
            pk[1] = (_Float16)(C[8 + uu][i]  + b1);
            pk[2] = (_Float16)(C[16 + uu][i] + b2);
            pk[3] = (_Float16)(C[24 + uu][i] + b3);
            ((f16x4*)out)[(size_t)row * 128 + uu * 16 + c] = pk;
        }
    }
}

// ---------------- KF: fused two-layer recurrence + chunked xgate + FC -----
__global__ __launch_bounds__(512, 1) void lstm_fused(
    const float* __restrict__ whh0, const float* __restrict__ wih1,
    const float* __restrict__ whh1,
    const float* __restrict__ bih1, const float* __restrict__ bhh1,
    const _Float16* __restrict__ xg0,   // [B*T][unit][4g] fp16 (bias incl.)
    const float* __restrict__ fc_w, const float* __restrict__ fc_b,
    float* __restrict__ out)
{
    const int t = threadIdx.x;
    const int b = blockIdx.x;
    const int w = t >> 6;
    const int l = t & 63;
    const int q = l >> 4;        // quad 0..3
    const int c = l & 15;
    const int unit = (w << 4) + c;   // 0..127

    // Wih1 fp16 in LDS, chunk-XOR swizzle (phase-only reads).
    __shared__ __align__(16) _Float16 w1lds[512 * 128];        // 128 KB
    // h0 ring of current chunk: UNswizzled, padded rows (272B stride).
    __shared__ __align__(16) _Float16 h0tile[CH * HP];         // 4352 B
    __shared__ __align__(16) _Float16 h1buf[2][128];           //  512 B
    // xg1 of chunk being consumed: [time][unit][4g] f16x4 per unit.
    __shared__ __align__(16) _Float16 xg1t[CH * 512];          //  16 KB
    __shared__ float redbuf[128];

    // ---- stage Wih1 -> LDS (one row per thread, cvt + chunk swizzle) ----
    {
        const int r = t;
        const float* src = wih1 + (size_t)r * 128;
        #pragma unroll
        for (int j = 0; j < 16; ++j) {
            float4 v0 = ((const float4*)src)[2 * j];
            float4 v1 = ((const float4*)src)[2 * j + 1];
            f16x8 f;
            f[0] = (_Float16)v0.x; f[1] = (_Float16)v0.y;
            f[2] = (_Float16)v0.z; f[3] = (_Float16)v0.w;
            f[4] = (_Float16)v1.x; f[5] = (_Float16)v1.y;
            f[6] = (_Float16)v1.z; f[7] = (_Float16)v1.w;
            *(f16x8*)&w1lds[r * 128 + ((j ^ (r & 7)) << 3)] = f;
        }
    }

    // ---- resident B-frags: Whh0, Whh1 rows g*128+unit, k = kt*32+q*8 ----
    f16x8 B0[4][4], B1[4][4];
    #pragma unroll
    for (int g = 0; g < 4; ++g) {
        #pragma unroll
        for (int kt = 0; kt < 4; ++kt) {
            const size_t off = (size_t)((g << 7) + unit) * 128 + (kt << 5) + (q << 3);
            {
                float4 v0 = ((const float4*)(whh0 + off))[0];
                float4 v1 = ((const float4*)(whh0 + off))[1];
                f16x8 f;
                f[0] = (_Float16)v0.x; f[1] = (_Float16)v0.y;
                f[2] = (_Float16)v0.z; f[3] = (_Float16)v0.w;
                f[4] = (_Float16)v1.x; f[5] = (_Float16)v1.y;
                f[6] = (_Float16)v1.z; f[7] = (_Float16)v1.w;
                B0[g][kt] = f;
            }
            {
                float4 v0 = ((const float4*)(whh1 + off))[0];
                float4 v1 = ((const float4*)(whh1 + off))[1];
                f16x8 f;
                f[0] = (_Float16)v0.x; f[1] = (_Float16)v0.y;
                f[2] = (_Float16)v0.z; f[3] = (_Float16)v0.w;
                f[4] = (_Float16)v1.x; f[5] = (_Float16)v1.y;
                f[6] = (_Float16)v1.z; f[7] = (_Float16)v1.w;
                B1[g][kt] = f;
            }
        }
    }

    // phase bias: lane holds all 4 gates of its unit.
    float bias1g[4];
    #pragma unroll
    for (int g = 0; g < 4; ++g)
        bias1g[g] = bih1[(g << 7) + unit] + bhh1[(g << 7) + unit];

    // zero: xg1t (k=0 zero-dynamics), h1buf, h0 ring slot 15.
    for (int i = t; i < CH * 512 / 8; i += 512)
        ((float4*)xg1t)[i] = make_float4(0.f, 0.f, 0.f, 0.f);
    if (t < 128) {
        h1buf[0][t] = (_Float16)0.f;
        h1buf[1][t] = (_Float16)0.f;
        h0tile[(CH - 1) * HP + t] = (_Float16)0.f;
    }

    // xg0 rotating prefetch regs (depth 2).
    const f16x4* __restrict__ xgp = (const f16x4*)xg0 + (size_t)b * TT * 128 + unit;
    f16x4 xr[4];
    xr[0] = xgp[0];
    xr[1] = xgp[128];
    xr[2] = xr[0]; xr[3] = xr[0];   // overwritten before first use

    // persistent accumulators; only [0] is ever read (stale-lane trick).
    f32x4 a0[4], a1[4];
    #pragma unroll
    for (int g = 0; g < 4; ++g) {
        a0[g] = (f32x4){0.f, 0.f, 0.f, 0.f};
        a1[g] = (f32x4){0.f, 0.f, 0.f, 0.f};
    }

    float cst0 = 0.f, cst1 = 0.f;
    __syncthreads();

    #pragma unroll 1
    for (int k = 0; k <= NCH; ++k) {
        #pragma unroll
        for (int j = 0; j < CH; ++j) {
            const int rp = (j + CH - 1) & (CH - 1);

            // gate inputs (C-in element 0 only; [1..3] stale, never read)
            f16x4 xv = xr[j & 3];
            f16x4 xg1v = *(const f16x4*)&xg1t[(j << 9) + (unit << 2)];
            #pragma unroll
            for (int g = 0; g < 4; ++g) {
                a0[g][0] = (float)xv[g];
                a1[g][0] = (float)xg1v[g];
            }
            // prefetch xg0 for step s+2 (rotates into a different slot)
            xr[(j + 2) & 3] = xgp[(size_t)(k * CH + j + 2) * 128];

            // MFMA: broadcast-row A-frags; static LDS offsets (unrolled)
            #pragma unroll
            for (int kt = 0; kt < 4; ++kt) {
                f16x8 Af0 = *(const f16x8*)&h0tile[rp * HP + (kt << 5) + (q << 3)];
                f16x8 Af1 = *(const f16x8*)&h1buf[(j & 1) ^ 1][(kt << 5) + (q << 3)];
                #pragma unroll
                for (int g = 0; g < 4; ++g)
                    a0[g] = __builtin_amdgcn_mfma_f32_16x16x32_f16(Af0, B0[g][kt], a0[g], 0, 0, 0);
                #pragma unroll
                for (int g = 0; g < 4; ++g)
                    a1[g] = __builtin_amdgcn_mfma_f32_16x16x32_f16(Af1, B1[g][kt], a1[g], 0, 0, 0);
            }

            // L0 activation
            {
                float gi = sigm_f(a0[0][0]);
                float gf = sigm_f(a0[1][0]);
                float gg = tanh_f(a0[2][0]);
                float go = sigm_f(a0[3][0]);
                cst0 = gf * cst0 + gi * gg;
                float hh = go * tanh_f(cst0);
                if (l < 16) h0tile[j * HP + unit] = (_Float16)hh;
            }
            // L1 activation (k=0 runs exact zero-dynamics: stays 0)
            {
                float gi = sigm_f(a1[0][0]);
                float gf = sigm_f(a1[1][0]);
                float gg = tanh_f(a1[2][0]);
                float go = sigm_f(a1[3][0]);
                cst1 = gf * cst1 + gi * gg;
                float hh = go * tanh_f(cst1);
                if (l < 16) {
                    h1buf[j & 1][unit] = (_Float16)hh;
                    if (j == CH - 1) redbuf[unit] = hh;  // final chunk's wins
                }
            }
            __syncthreads();
        }

        // ---- xgate GEMM phase: xg1t = h0tile(chunk k) @ Wih1^T + b1 ----
        if (k < NCH) {
            f32x4 G[4];
            #pragma unroll
            for (int g = 0; g < 4; ++g)
                G[g] = (f32x4){bias1g[g], bias1g[g], bias1g[g], bias1g[g]};
            #pragma unroll
            for (int kt = 0; kt < 4; ++kt) {
                // A rows = 16 timesteps (lane c -> row c); padded stride
                f16x8 Ag = *(const f16x8*)&h0tile[c * HP + (kt << 5) + (q << 3)];
                #pragma unroll
                for (int g = 0; g < 4; ++g) {
                    const int r = (g << 7) + unit;   // tiles {g*8+w}
                    f16x8 Bg = *(const f16x8*)&w1lds[r * 128 +
                                   ((((kt << 2) + q) ^ (c & 7)) << 3)];
                    G[g] = __builtin_amdgcn_mfma_f32_16x16x32_f16(Ag, Bg, G[g], 0, 0, 0);
                }
            }
            // lane holds all 4 gates of `unit` for rows q*4+i2 -> packed 8B
            #pragma unroll
            for (int i2 = 0; i2 < 4; ++i2) {
                f16x4 pk;
                pk[0] = (_Float16)G[0][i2];
                pk[1] = (_Float16)G[1][i2];
                pk[2] = (_Float16)G[2][i2];
                pk[3] = (_Float16)G[3][i2];
                *(f16x4*)&xg1t[(((q << 2) + i2) << 9) + (unit << 2)] = pk;
            }
            __syncthreads();
        }
    }

    // fused FC on h1(T-1)
    if (t < 64) {
        float p = redbuf[t] * fc_w[t] + redbuf[t + 64] * fc_w[t + 64];
        #pragma unroll
        for (int off = 32; off > 0; off >>= 1) p += __shfl_down(p, off, 64);
        if (t == 0) out[b] = p + fc_b[0];
    }
}

extern "C" void kernel_launch(void* const* d_in, const int* in_sizes, int n_in,
                              void* d_out, int out_size, void* d_ws, size_t ws_size,
                              hipStream_t stream) {
    const float* x     = (const float*)d_in[0];
    const float* w_ih0 = (const float*)d_in[1];
    const float* w_hh0 = (const float*)d_in[2];
    const float* b_ih0 = (const float*)d_in[3];
    const float* b_hh0 = (const float*)d_in[4];
    const float* w_ih1 = (const float*)d_in[5];
    const float* w_hh1 = (const float*)d_in[6];
    const float* b_ih1 = (const float*)d_in[7];
    const float* b_hh1 = (const float*)d_in[8];
    const float* fc_w  = (const float*)d_in[9];
    const float* fc_b  = (const float*)d_in[10];
    float* out = (float*)d_out;

    // ws layout (bytes): xg [134217728] + 64KB OOB-prefetch slack + w0_16
    char* ws = (char*)d_ws;
    _Float16* xg    = (_Float16*)(ws);
    _Float16* w0_16 = (_Float16*)(ws + 134217728 + 65536);

    // K0: w_ih0 cvt only (x cvt fused into gemm)
    cvt_f32_f16<<<dim3(32), dim3(256), 0, stream>>>(w_ih0, w0_16, (512 * 64) / 4);

    // KG: xg0 = x . Wih0^T + (b_ih0 + b_hh0), gate-packed output
    gemm_xg0<<<dim3(MM / 64), dim3(256), 0, stream>>>(x, w0_16, b_ih0, b_hh0, xg);

    // KF: both layers + chunked xgate + FC
    lstm_fused<<<dim3(256), dim3(512), 0, stream>>>(w_hh0, w_ih1, w_hh1,
                                                    b_ih1, b_hh1, xg,
                                                    fc_w, fc_b, out);
}